// Round 2
// baseline (3298.346 us; speedup 1.0000x reference)
//
#include <hip/hip_runtime.h>
#include <hip/hip_bf16.h>
#include <cstdint>

#define LCONST 12
#define BCONST 8
#define SCONST 512
#define DCONST 768
#define HCONST 12
#define FCONST 3072
#define DH 64

typedef __bf16 bf16x8 __attribute__((ext_vector_type(8)));
typedef float f32x4 __attribute__((ext_vector_type(4)));

// async global -> LDS, 16B per lane. LDS dst must be wave-uniform base;
// HW writes base + lane*16. Global src is per-lane.
__device__ __forceinline__ void gload16(const void* g, void* l) {
    __builtin_amdgcn_global_load_lds(
            (const __attribute__((address_space(1))) void*)g,
            (__attribute__((address_space(3))) void*)l, 16, 0, 0);
}

// ---------------------------------------------------------------------------
// relative position bucket helpers (match jnp._rel_bucket exactly)
// ---------------------------------------------------------------------------
__device__ __forceinline__ int rbucket(int rel, int nb2, int maxex) {
    int ret = (rel > 0) ? nb2 : 0;
    int n = (rel < 0) ? -rel : rel;
    if (n < maxex) return ret + n;
    const float inv_ln16 = 0.36067376022224085f;  // 1/ln(16)
    int v = maxex + (int)(logf((float)n / (float)maxex) * inv_ln16 * (float)(nb2 - maxex));
    if (v > nb2 - 1) v = nb2 - 1;
    return ret + v;
}

__global__ __launch_bounds__(256) void build_idx_kernel(
        const int* __restrict__ pos, const int* __restrict__ bbox,
        int* __restrict__ idx) {
    size_t t = (size_t)blockIdx.x * 256 + threadIdx.x;  // B*S*S total
    int j = (int)(t & 511);
    int i = (int)((t >> 9) & 511);
    int b = (int)(t >> 18);
    int rp = rbucket(pos[b * SCONST + j] - pos[b * SCONST + i], 16, 8);
    int cxi = bbox[((size_t)b * SCONST + i) * 4 + 0];
    int cxj = bbox[((size_t)b * SCONST + j) * 4 + 0];
    int cyi = bbox[((size_t)b * SCONST + i) * 4 + 3];
    int cyj = bbox[((size_t)b * SCONST + j) * 4 + 3];
    int bx = rbucket(cxj - cxi, 32, 16);
    int by = rbucket(cyj - cyi, 32, 16);
    idx[t] = rp | (bx << 5) | (by << 11);
}

__global__ __launch_bounds__(256) void cvt_kernel(const float* __restrict__ in,
                                                  __bf16* __restrict__ out, int n) {
    int t = blockIdx.x * 256 + threadIdx.x;
    if (t < n) out[t] = (__bf16)in[t];
}

// ---------------------------------------------------------------------------
// transpose + convert: in (R x C) f32 row-major -> out (C x R) bf16 row-major
// blockIdx.y selects layer (batched over L when gridDim.y==L)
// ---------------------------------------------------------------------------
__global__ __launch_bounds__(256) void transpose_cvt_kernel(
        const float* __restrict__ in, __bf16* __restrict__ out, int R, int C) {
    __shared__ float tile[32][33];
    size_t off = (size_t)blockIdx.y * R * C;
    int nct = C >> 5;
    int c0 = (blockIdx.x % nct) << 5;
    int r0 = (blockIdx.x / nct) << 5;
    int tx = threadIdx.x & 31, ty = threadIdx.x >> 5;  // 32 x 8
#pragma unroll
    for (int i = 0; i < 32; i += 8)
        tile[ty + i][tx] = in[off + (size_t)(r0 + ty + i) * C + c0 + tx];
    __syncthreads();
#pragma unroll
    for (int i = 0; i < 32; i += 8)
        out[off + (size_t)(c0 + ty + i) * R + r0 + tx] = (__bf16)tile[tx][ty + i];
}

// ---------------------------------------------------------------------------
// GEMM: C(MxN) = A(MxK) @ W(KxN), W given as Bt = W^T (N x K), bf16 in,
// fp32 accum, m97-style global_load_lds staging, epilogue by MODE.
// ---------------------------------------------------------------------------
template <int MODE>
__global__ __launch_bounds__(256) void gemm_kernel(
        const __bf16* __restrict__ A, const __bf16* __restrict__ Bt,
        int M, int N, int K,
        const float* __restrict__ cbias, const float* __restrict__ vbias,
        const float* __restrict__ resid, float* __restrict__ outF,
        __bf16* __restrict__ outQ, __bf16* __restrict__ outK,
        __bf16* __restrict__ outV, __bf16* __restrict__ outB) {
    __shared__ __align__(16) __bf16 As[128 * 32];
    __shared__ __align__(16) __bf16 Bs[128 * 32];
    int tid = threadIdx.x;
    int wid = tid >> 6, lane = tid & 63, quad = lane >> 4, l16 = lane & 15;
    int nTM = M >> 7;
    int tileM = (blockIdx.x % nTM) << 7;
    int tileN = (blockIdx.x / nTM) << 7;
    int wm = wid >> 1, wn = wid & 1;

    // staging: wave wid owns rows [wid*32, wid*32+32) of both tiles.
    // chunk s in {0,1}: rows wid*32+s*16 .. +16; lane covers row lane/4,
    // 16B slice (lane&3)*8 elems. LDS layout [row][32k] contiguous matches
    // the HW's base+lane*16 ordering exactly (no padding allowed).
    const __bf16* gA0 = A + (size_t)(tileM + wid * 32 + (lane >> 2)) * K + ((lane & 3) << 3);
    const __bf16* gB0 = Bt + (size_t)(tileN + wid * 32 + (lane >> 2)) * K + ((lane & 3) << 3);
    __bf16* lA0 = As + wid * 1024;
    __bf16* lB0 = Bs + wid * 1024;

    f32x4 acc[4][4] = {};

    for (int k0 = 0; k0 < K; k0 += 32) {
        gload16(gA0 + k0, lA0);
        gload16(gA0 + (size_t)16 * K + k0, lA0 + 512);
        gload16(gB0 + k0, lB0);
        gload16(gB0 + (size_t)16 * K + k0, lB0 + 512);
        __syncthreads();
        bf16x8 af[4], bfr[4];
#pragma unroll
        for (int mt = 0; mt < 4; mt++)
            af[mt] = *(const bf16x8*)&As[(wm * 64 + mt * 16 + l16) * 32 + quad * 8];
#pragma unroll
        for (int nt = 0; nt < 4; nt++)
            bfr[nt] = *(const bf16x8*)&Bs[(wn * 64 + nt * 16 + l16) * 32 + quad * 8];
#pragma unroll
        for (int mt = 0; mt < 4; mt++)
#pragma unroll
            for (int nt = 0; nt < 4; nt++)
                acc[mt][nt] = __builtin_amdgcn_mfma_f32_16x16x32_bf16(
                        af[mt], bfr[nt], acc[mt][nt], 0, 0, 0);
        __syncthreads();
    }

#pragma unroll
    for (int mt = 0; mt < 4; mt++)
#pragma unroll
        for (int nt = 0; nt < 4; nt++)
#pragma unroll
            for (int r = 0; r < 4; r++) {
                int row = tileM + wm * 64 + mt * 16 + quad * 4 + r;
                int col = tileN + wn * 64 + nt * 16 + l16;
                float v = acc[mt][nt][r];
                if (MODE == 0) {
                    int b = row >> 9, s = row & 511;
                    if (col < 768) {
                        int h = col >> 6, dh = col & 63;
                        float q = (v + cbias[col]) * 0.125f;
                        outQ[(((size_t)b * HCONST + h) * SCONST + s) * DH + dh] = (__bf16)q;
                    } else if (col < 1536) {
                        int c2 = col - 768;
                        int h = c2 >> 6, dh = c2 & 63;
                        outK[(((size_t)b * HCONST + h) * SCONST + s) * DH + dh] = (__bf16)v;
                    } else {
                        int c2 = col - 1536;
                        int h = c2 >> 6, dh = c2 & 63;
                        float vv = v + vbias[c2];
                        outV[(((size_t)b * HCONST + h) * DH + dh) * SCONST + s] = (__bf16)vv;
                    }
                } else if (MODE == 1 || MODE == 3) {
                    size_t o = (size_t)row * N + col;
                    outF[o] = v + cbias[col] + resid[o];
                } else {  // MODE 2: exact gelu
                    float u = v + cbias[col];
                    float g = 0.5f * u * (1.0f + erff(u * 0.70710678118654752f));
                    outB[(size_t)row * N + col] = (__bf16)g;
                }
            }
}

// ---------------------------------------------------------------------------
// fused flash attention per (b,h) x 64-query block.
// ---------------------------------------------------------------------------
__global__ __launch_bounds__(256) void attn_kernel(
        const __bf16* __restrict__ qbuf, const __bf16* __restrict__ kbuf,
        const __bf16* __restrict__ vbuf, const int* __restrict__ idx,
        const int* __restrict__ amask, const float* __restrict__ tpg,
        const float* __restrict__ txg, const float* __restrict__ tyg,
        __bf16* __restrict__ ctx) {
    int bh = blockIdx.x >> 3;          // b*H + h
    int i0 = (blockIdx.x & 7) << 6;    // query block start
    int b = bh / HCONST, h = bh % HCONST;

    __shared__ __align__(16) __bf16 Ks[64 * 64];
    __shared__ __align__(16) __bf16 Vs[64 * 64];      // transposed: [dh][key]
    __shared__ __align__(16) __bf16 Ps[4][16 * 64];   // per-wave P tile
    __shared__ float tp[32], tx[64], ty[64];
    __shared__ float mk[512];

    int tid = threadIdx.x;
    if (tid < 32) tp[tid] = tpg[tid * HCONST + h];
    if (tid < 64) {
        tx[tid] = txg[tid * HCONST + h];
        ty[tid] = tyg[tid * HCONST + h];
    }
    for (int j = tid; j < 512; j += 256)
        mk[j] = amask[b * SCONST + j] ? -INFINITY : 0.0f;

    int wid = tid >> 6, lane = tid & 63, quad = lane >> 4, l16 = lane & 15;

    const __bf16* qrow = qbuf + ((size_t)bh * SCONST + i0 + wid * 16 + l16) * DH;
    bf16x8 qf0 = *(const bf16x8*)(qrow + quad * 8);
    bf16x8 qf1 = *(const bf16x8*)(qrow + 32 + quad * 8);

    const __bf16* kg = kbuf + (size_t)bh * SCONST * DH;
    const __bf16* vg = vbuf + (size_t)bh * DH * SCONST;

    f32x4 O[4] = {};
    float m_r[4] = {-1e30f, -1e30f, -1e30f, -1e30f};
    float l_r[4] = {0.f, 0.f, 0.f, 0.f};

    __syncthreads();  // tp/tx/ty/mk ready

    for (int j0 = 0; j0 < SCONST; j0 += 64) {
        // stage K tile (contiguous 8KB) and V^T tile via global_load_lds
        {
            const __bf16* kbase = kg + (size_t)j0 * DH;
#pragma unroll
            for (int s = 0; s < 2; s++) {
                int c = wid * 2 + s;
                gload16(kbase + c * 512 + lane * 8, Ks + c * 512);
                int dh = c * 8 + (lane >> 3), cc = lane & 7;
                gload16(vg + (size_t)dh * SCONST + j0 + cc * 8, Vs + c * 512);
            }
        }
        __syncthreads();

        // QK^T : 16 queries x 64 keys per wave
        float sc[4][4];  // [jt][r]
#pragma unroll
        for (int jt = 0; jt < 4; jt++) {
            f32x4 a = {};
            bf16x8 kf0 = *(const bf16x8*)&Ks[(jt * 16 + l16) * 64 + quad * 8];
            bf16x8 kf1 = *(const bf16x8*)&Ks[(jt * 16 + l16) * 64 + 32 + quad * 8];
            a = __builtin_amdgcn_mfma_f32_16x16x32_bf16(qf0, kf0, a, 0, 0, 0);
            a = __builtin_amdgcn_mfma_f32_16x16x32_bf16(qf1, kf1, a, 0, 0, 0);
#pragma unroll
            for (int r = 0; r < 4; r++) {
                int i = i0 + wid * 16 + quad * 4 + r;
                int j = j0 + jt * 16 + l16;
                int pk = idx[((size_t)b * SCONST + i) * SCONST + j];
                float bias = tp[pk & 31] + tx[(pk >> 5) & 63] + ty[(pk >> 11) & 63];
                sc[jt][r] = a[r] + bias + mk[j];
            }
        }

        // online softmax (rows live across the 16 lanes of each quad)
        float p[4][4];
#pragma unroll
        for (int r = 0; r < 4; r++) {
            float mb = fmaxf(fmaxf(sc[0][r], sc[1][r]), fmaxf(sc[2][r], sc[3][r]));
#pragma unroll
            for (int m = 1; m < 16; m <<= 1) mb = fmaxf(mb, __shfl_xor(mb, m, 64));
            float mn = fmaxf(m_r[r], mb);
            float alpha = __expf(m_r[r] - mn);
            m_r[r] = mn;
            float ls = 0.f;
#pragma unroll
            for (int jt = 0; jt < 4; jt++) {
                float pv = __expf(sc[jt][r] - mn);
                p[jt][r] = pv;
                ls += pv;
            }
#pragma unroll
            for (int m = 1; m < 16; m <<= 1) ls += __shfl_xor(ls, m, 64);
            l_r[r] = l_r[r] * alpha + ls;
#pragma unroll
            for (int nt = 0; nt < 4; nt++) O[nt][r] *= alpha;
        }

        // P (C-layout) -> LDS -> A-layout
        __bf16* pl = &Ps[wid][0];
#pragma unroll
        for (int jt = 0; jt < 4; jt++)
#pragma unroll
            for (int r = 0; r < 4; r++)
                pl[(quad * 4 + r) * 64 + jt * 16 + l16] = (__bf16)p[jt][r];

        bf16x8 pa0 = *(const bf16x8*)&pl[l16 * 64 + quad * 8];
        bf16x8 pa1 = *(const bf16x8*)&pl[l16 * 64 + 32 + quad * 8];
#pragma unroll
        for (int nt = 0; nt < 4; nt++) {
            bf16x8 vb0 = *(const bf16x8*)&Vs[(nt * 16 + l16) * 64 + quad * 8];
            bf16x8 vb1 = *(const bf16x8*)&Vs[(nt * 16 + l16) * 64 + 32 + quad * 8];
            O[nt] = __builtin_amdgcn_mfma_f32_16x16x32_bf16(pa0, vb0, O[nt], 0, 0, 0);
            O[nt] = __builtin_amdgcn_mfma_f32_16x16x32_bf16(pa1, vb1, O[nt], 0, 0, 0);
        }
        __syncthreads();
    }

#pragma unroll
    for (int nt = 0; nt < 4; nt++)
#pragma unroll
        for (int r = 0; r < 4; r++) {
            int i = i0 + wid * 16 + quad * 4 + r;
            int dh = nt * 16 + l16;
            float o = O[nt][r] / l_r[r];
            ctx[((size_t)b * SCONST + i) * DCONST + h * DH + dh] = (__bf16)o;
        }
}

// ---------------------------------------------------------------------------
// LayerNorm over D=768, fp32 in -> fp32 out + bf16 copy
// ---------------------------------------------------------------------------
__global__ __launch_bounds__(256) void ln_kernel(
        const float* __restrict__ in, const float* __restrict__ g,
        const float* __restrict__ bb, float* __restrict__ outF,
        __bf16* __restrict__ outB) {
    __shared__ float red[4];
    int row = blockIdx.x, t = threadIdx.x;
    const float* x = in + (size_t)row * DCONST;
    float v0 = x[t], v1 = x[t + 256], v2 = x[t + 512];
    float s = v0 + v1 + v2;
#pragma unroll
    for (int m = 1; m < 64; m <<= 1) s += __shfl_xor(s, m, 64);
    if ((t & 63) == 0) red[t >> 6] = s;
    __syncthreads();
    s = red[0] + red[1] + red[2] + red[3];
    __syncthreads();
    float mu = s * (1.0f / 768.0f);
    float d0 = v0 - mu, d1 = v1 - mu, d2 = v2 - mu;
    float q = d0 * d0 + d1 * d1 + d2 * d2;
#pragma unroll
    for (int m = 1; m < 64; m <<= 1) q += __shfl_xor(q, m, 64);
    if ((t & 63) == 0) red[t >> 6] = q;
    __syncthreads();
    q = red[0] + red[1] + red[2] + red[3];
    float rstd = rsqrtf(q * (1.0f / 768.0f) + 1e-12f);
    float y0 = d0 * rstd * g[t] + bb[t];
    float y1 = d1 * rstd * g[t + 256] + bb[t + 256];
    float y2 = d2 * rstd * g[t + 512] + bb[t + 512];
    size_t o = (size_t)row * DCONST;
    outF[o + t] = y0;
    outF[o + t + 256] = y1;
    outF[o + t + 512] = y2;
    outB[o + t] = (__bf16)y0;
    outB[o + t + 256] = (__bf16)y1;
    outB[o + t + 512] = (__bf16)y2;
}

// ---------------------------------------------------------------------------
extern "C" void kernel_launch(void* const* d_in, const int* in_sizes, int n_in,
                              void* d_out, int out_size, void* d_ws, size_t ws_size,
                              hipStream_t stream) {
    const float* hidden = (const float*)d_in[0];
    const int* amask = (const int*)d_in[1];
    const int* pos = (const int*)d_in[2];
    const int* bbox = (const int*)d_in[3];
    const float* qkv_w = (const float*)d_in[4];
    const float* q_bias = (const float*)d_in[5];
    const float* v_bias = (const float*)d_in[6];
    const float* aow = (const float*)d_in[7];
    const float* aob = (const float*)d_in[8];
    const float* ln1g = (const float*)d_in[9];
    const float* ln1b = (const float*)d_in[10];
    const float* iw = (const float*)d_in[11];
    const float* ib = (const float*)d_in[12];
    const float* fow = (const float*)d_in[13];
    const float* fob = (const float*)d_in[14];
    const float* ln2g = (const float*)d_in[15];
    const float* ln2b = (const float*)d_in[16];
    const float* tpt = (const float*)d_in[17];
    const float* txt = (const float*)d_in[18];
    const float* tyt = (const float*)d_in[19];
    float* out = (float*)d_out;

    char* w = (char*)d_ws;
    size_t used = 0;
    auto carve = [&](size_t bytes) {
        char* p = w + used;
        used += (bytes + 255) & ~(size_t)255;
        return p;
    };
    const size_t MT = 4096;  // B*S
    __bf16* qbuf = (__bf16*)carve(MT * 768 * 2);
    __bf16* kbuf = (__bf16*)carve(MT * 768 * 2);
    __bf16* vbuf = (__bf16*)carve(MT * 768 * 2);
    __bf16* xbf = (__bf16*)carve(MT * 768 * 2);
    __bf16* ctxbf = (__bf16*)carve(MT * 768 * 2);
    float* attnf = (float*)carve(MT * 768 * 4);
    __bf16* attnbf = (__bf16*)carve(MT * 768 * 2);
    __bf16* ffbf = (__bf16*)carve(MT * 3072 * 2);
    float* t1 = (float*)carve(MT * 768 * 4);
    int* idxb = (int*)carve((size_t)BCONST * SCONST * SCONST * 4);

    const size_t wq_sz = (size_t)2304 * 768 * 2;
    const size_t wa_sz = (size_t)768 * 768 * 2;
    const size_t wi_sz = (size_t)3072 * 768 * 2;
    const size_t wf_sz = (size_t)768 * 3072 * 2;
    const size_t wsum = wq_sz + wa_sz + wi_sz + wf_sz;
    // full path: all 12 layers' transposed weights resident (4 batched launches)
    bool full = (ws_size >= used + 12 * wsum + (12 * 4 + 4) * 256);
    int nlw = full ? 12 : 1;
    __bf16* wqT = (__bf16*)carve(wq_sz * nlw);
    __bf16* waT = (__bf16*)carve(wa_sz * nlw);
    __bf16* wiT = (__bf16*)carve(wi_sz * nlw);
    __bf16* wfT = (__bf16*)carve(wf_sz * nlw);

    build_idx_kernel<<<(BCONST * SCONST * SCONST) / 256, 256, 0, stream>>>(pos, bbox, idxb);
    cvt_kernel<<<(int)(MT * 768 / 256), 256, 0, stream>>>(hidden, xbf, (int)(MT * 768));

    if (full) {
        transpose_cvt_kernel<<<dim3((2304 / 32) * (768 / 32), 12), 256, 0, stream>>>(
                qkv_w, wqT, 768, 2304);
        transpose_cvt_kernel<<<dim3((768 / 32) * (768 / 32), 12), 256, 0, stream>>>(
                aow, waT, 768, 768);
        transpose_cvt_kernel<<<dim3((3072 / 32) * (768 / 32), 12), 256, 0, stream>>>(
                iw, wiT, 768, 3072);
        transpose_cvt_kernel<<<dim3((768 / 32) * (3072 / 32), 12), 256, 0, stream>>>(
                fow, wfT, 3072, 768);
    }

    for (int l = 0; l < LCONST; l++) {
        __bf16* wq_l = wqT + (full ? (size_t)l * 2304 * 768 : 0);
        __bf16* wa_l = waT + (full ? (size_t)l * 768 * 768 : 0);
        __bf16* wi_l = wiT + (full ? (size_t)l * 3072 * 768 : 0);
        __bf16* wf_l = wfT + (full ? (size_t)l * 768 * 3072 : 0);
        if (!full) {
            transpose_cvt_kernel<<<dim3((2304 / 32) * (768 / 32), 1), 256, 0, stream>>>(
                    qkv_w + (size_t)l * 768 * 2304, wq_l, 768, 2304);
            transpose_cvt_kernel<<<dim3((768 / 32) * (768 / 32), 1), 256, 0, stream>>>(
                    aow + (size_t)l * 768 * 768, wa_l, 768, 768);
            transpose_cvt_kernel<<<dim3((3072 / 32) * (768 / 32), 1), 256, 0, stream>>>(
                    iw + (size_t)l * 768 * 3072, wi_l, 768, 3072);
            transpose_cvt_kernel<<<dim3((768 / 32) * (3072 / 32), 1), 256, 0, stream>>>(
                    fow + (size_t)l * 3072 * 768, wf_l, 3072, 768);
        }

        gemm_kernel<0><<<(4096 / 128) * (2304 / 128), 256, 0, stream>>>(
                xbf, wq_l, 4096, 2304, 768, q_bias + (size_t)l * 768,
                v_bias + (size_t)l * 768, nullptr, nullptr, qbuf, kbuf, vbuf, nullptr);

        attn_kernel<<<BCONST * HCONST * (SCONST / 64), 256, 0, stream>>>(
                qbuf, kbuf, vbuf, idxb, amask, tpt, txt, tyt, ctxbf);

        const float* xres = (l == 0) ? hidden : out;
        gemm_kernel<1><<<(4096 / 128) * (768 / 128), 256, 0, stream>>>(
                ctxbf, wa_l, 4096, 768, 768, aob + (size_t)l * 768, nullptr, xres, t1,
                nullptr, nullptr, nullptr, nullptr);
        ln_kernel<<<4096, 256, 0, stream>>>(t1, ln1g + (size_t)l * 768,
                                            ln1b + (size_t)l * 768, attnf, attnbf);

        gemm_kernel<2><<<(4096 / 128) * (3072 / 128), 256, 0, stream>>>(
                attnbf, wi_l, 4096, 3072, 768, ib + (size_t)l * 3072, nullptr, nullptr,
                nullptr, nullptr, nullptr, nullptr, ffbf);

        gemm_kernel<3><<<(4096 / 128) * (768 / 128), 256, 0, stream>>>(
                ffbf, wf_l, 4096, 768, 3072, fob + (size_t)l * 768, nullptr, attnf, t1,
                nullptr, nullptr, nullptr, nullptr);
        ln_kernel<<<4096, 256, 0, stream>>>(t1, ln2g + (size_t)l * 768,
                                            ln2b + (size_t)l * 768, out, xbf);
    }
}

// Round 3
// 2886.660 us; speedup vs baseline: 1.1426x; 1.1426x over previous
//
#include <hip/hip_runtime.h>
#include <hip/hip_bf16.h>
#include <cstdint>

#define LCONST 12
#define BCONST 8
#define SCONST 512
#define DCONST 768
#define HCONST 12
#define FCONST 3072
#define DH 64

typedef __bf16 bf16x8 __attribute__((ext_vector_type(8)));
typedef float f32x4 __attribute__((ext_vector_type(4)));

// async global -> LDS, 16B per lane. LDS dst must be wave-uniform base;
// HW writes base + lane*16. Global src is per-lane.
__device__ __forceinline__ void gload16(const void* g, void* l) {
    __builtin_amdgcn_global_load_lds(
            (const __attribute__((address_space(1))) void*)g,
            (__attribute__((address_space(3))) void*)l, 16, 0, 0);
}

// ---------------------------------------------------------------------------
// relative position bucket helpers (match jnp._rel_bucket exactly)
// ---------------------------------------------------------------------------
__device__ __forceinline__ int rbucket(int rel, int nb2, int maxex) {
    int ret = (rel > 0) ? nb2 : 0;
    int n = (rel < 0) ? -rel : rel;
    if (n < maxex) return ret + n;
    const float inv_ln16 = 0.36067376022224085f;  // 1/ln(16)
    int v = maxex + (int)(logf((float)n / (float)maxex) * inv_ln16 * (float)(nb2 - maxex));
    if (v > nb2 - 1) v = nb2 - 1;
    return ret + v;
}

__global__ __launch_bounds__(256) void build_idx_kernel(
        const int* __restrict__ pos, const int* __restrict__ bbox,
        int* __restrict__ idx) {
    size_t t = (size_t)blockIdx.x * 256 + threadIdx.x;  // B*S*S total
    int j = (int)(t & 511);
    int i = (int)((t >> 9) & 511);
    int b = (int)(t >> 18);
    int rp = rbucket(pos[b * SCONST + j] - pos[b * SCONST + i], 16, 8);
    int cxi = bbox[((size_t)b * SCONST + i) * 4 + 0];
    int cxj = bbox[((size_t)b * SCONST + j) * 4 + 0];
    int cyi = bbox[((size_t)b * SCONST + i) * 4 + 3];
    int cyj = bbox[((size_t)b * SCONST + j) * 4 + 3];
    int bx = rbucket(cxj - cxi, 32, 16);
    int by = rbucket(cyj - cyi, 32, 16);
    idx[t] = rp | (bx << 5) | (by << 11);
}

__global__ __launch_bounds__(256) void cvt_kernel(const float* __restrict__ in,
                                                  __bf16* __restrict__ out, int n) {
    int t = blockIdx.x * 256 + threadIdx.x;
    if (t < n) out[t] = (__bf16)in[t];
}

// ---------------------------------------------------------------------------
// transpose + convert: in (R x C) f32 row-major -> out (C x R) bf16 row-major
// blockIdx.y selects layer (batched over L when gridDim.y==L)
// ---------------------------------------------------------------------------
__global__ __launch_bounds__(256) void transpose_cvt_kernel(
        const float* __restrict__ in, __bf16* __restrict__ out, int R, int C) {
    __shared__ float tile[32][33];
    size_t off = (size_t)blockIdx.y * R * C;
    int nct = C >> 5;
    int c0 = (blockIdx.x % nct) << 5;
    int r0 = (blockIdx.x / nct) << 5;
    int tx = threadIdx.x & 31, ty = threadIdx.x >> 5;  // 32 x 8
#pragma unroll
    for (int i = 0; i < 32; i += 8)
        tile[ty + i][tx] = in[off + (size_t)(r0 + ty + i) * C + c0 + tx];
    __syncthreads();
#pragma unroll
    for (int i = 0; i < 32; i += 8)
        out[off + (size_t)(c0 + ty + i) * R + r0 + tx] = (__bf16)tile[tx][ty + i];
}

// ---------------------------------------------------------------------------
// GEMM: C(MxN) = A(MxK) @ W(KxN), W given as Bt = W^T (N x K), bf16 in,
// fp32 accum, m97-style global_load_lds staging.
//  MODE 0: qkv epilogue (q bias+scale, k, v bias; scattered bf16)
//  MODE 2: gelu_exact(acc + cbias) -> outB
//  MODE 4: split-K partial: part[chunk][row][col] = acc  (chunk = blockIdx.y,
//          A/Bt offset by chunk*Kc along K; ldK = full K row stride)
// ---------------------------------------------------------------------------
template <int MODE>
__global__ __launch_bounds__(256) void gemm_kernel(
        const __bf16* __restrict__ A, const __bf16* __restrict__ Bt,
        int M, int N, int Kc, int ldK,
        const float* __restrict__ cbias, const float* __restrict__ vbias,
        float* __restrict__ part,
        __bf16* __restrict__ outQ, __bf16* __restrict__ outK,
        __bf16* __restrict__ outV, __bf16* __restrict__ outB) {
    __shared__ __align__(16) __bf16 As[128 * 32];
    __shared__ __align__(16) __bf16 Bs[128 * 32];
    int tid = threadIdx.x;
    int wid = tid >> 6, lane = tid & 63, quad = lane >> 4, l16 = lane & 15;
    int nTM = M >> 7;
    int tileM = (blockIdx.x % nTM) << 7;
    int tileN = (blockIdx.x / nTM) << 7;
    int chunk = blockIdx.y;
    int wm = wid >> 1, wn = wid & 1;

    const __bf16* Ab = A + (size_t)chunk * Kc;
    const __bf16* Bb = Bt + (size_t)chunk * Kc;
    const __bf16* gA0 = Ab + (size_t)(tileM + wid * 32 + (lane >> 2)) * ldK + ((lane & 3) << 3);
    const __bf16* gB0 = Bb + (size_t)(tileN + wid * 32 + (lane >> 2)) * ldK + ((lane & 3) << 3);
    __bf16* lA0 = As + wid * 1024;
    __bf16* lB0 = Bs + wid * 1024;

    f32x4 acc[4][4] = {};

    for (int k0 = 0; k0 < Kc; k0 += 32) {
        gload16(gA0 + k0, lA0);
        gload16(gA0 + (size_t)16 * ldK + k0, lA0 + 512);
        gload16(gB0 + k0, lB0);
        gload16(gB0 + (size_t)16 * ldK + k0, lB0 + 512);
        __syncthreads();
        bf16x8 af[4], bfr[4];
#pragma unroll
        for (int mt = 0; mt < 4; mt++)
            af[mt] = *(const bf16x8*)&As[(wm * 64 + mt * 16 + l16) * 32 + quad * 8];
#pragma unroll
        for (int nt = 0; nt < 4; nt++)
            bfr[nt] = *(const bf16x8*)&Bs[(wn * 64 + nt * 16 + l16) * 32 + quad * 8];
#pragma unroll
        for (int mt = 0; mt < 4; mt++)
#pragma unroll
            for (int nt = 0; nt < 4; nt++)
                acc[mt][nt] = __builtin_amdgcn_mfma_f32_16x16x32_bf16(
                        af[mt], bfr[nt], acc[mt][nt], 0, 0, 0);
        __syncthreads();
    }

#pragma unroll
    for (int mt = 0; mt < 4; mt++)
#pragma unroll
        for (int nt = 0; nt < 4; nt++)
#pragma unroll
            for (int r = 0; r < 4; r++) {
                int row = tileM + wm * 64 + mt * 16 + quad * 4 + r;
                int col = tileN + wn * 64 + nt * 16 + l16;
                float v = acc[mt][nt][r];
                if (MODE == 0) {
                    int b = row >> 9, s = row & 511;
                    if (col < 768) {
                        int h = col >> 6, dh = col & 63;
                        float q = (v + cbias[col]) * 0.125f;
                        outQ[(((size_t)b * HCONST + h) * SCONST + s) * DH + dh] = (__bf16)q;
                    } else if (col < 1536) {
                        int c2 = col - 768;
                        int h = c2 >> 6, dh = c2 & 63;
                        outK[(((size_t)b * HCONST + h) * SCONST + s) * DH + dh] = (__bf16)v;
                    } else {
                        int c2 = col - 1536;
                        int h = c2 >> 6, dh = c2 & 63;
                        float vv = v + vbias[c2];
                        outV[(((size_t)b * HCONST + h) * DH + dh) * SCONST + s] = (__bf16)vv;
                    }
                } else if (MODE == 2) {  // exact gelu
                    float u = v + cbias[col];
                    float g = 0.5f * u * (1.0f + erff(u * 0.70710678118654752f));
                    outB[(size_t)row * N + col] = (__bf16)g;
                } else {  // MODE 4: raw split-K partial
                    part[(size_t)chunk * M * N + (size_t)row * N + col] = v;
                }
            }
}

// ---------------------------------------------------------------------------
// fused flash attention per (b,h) x 64-query block.
// ---------------------------------------------------------------------------
__global__ __launch_bounds__(256) void attn_kernel(
        const __bf16* __restrict__ qbuf, const __bf16* __restrict__ kbuf,
        const __bf16* __restrict__ vbuf, const int* __restrict__ idx,
        const int* __restrict__ amask, const float* __restrict__ tpg,
        const float* __restrict__ txg, const float* __restrict__ tyg,
        __bf16* __restrict__ ctx) {
    int bh = blockIdx.x >> 3;          // b*H + h
    int i0 = (blockIdx.x & 7) << 6;    // query block start
    int b = bh / HCONST, h = bh % HCONST;

    __shared__ __align__(16) __bf16 Ks[64 * 64];
    __shared__ __align__(16) __bf16 Vs[64 * 64];      // transposed: [dh][key]
    __shared__ __align__(16) __bf16 Ps[4][16 * 64];   // per-wave P tile
    __shared__ float tp[32], tx[64], ty[64];
    __shared__ float mk[512];

    int tid = threadIdx.x;
    if (tid < 32) tp[tid] = tpg[tid * HCONST + h];
    if (tid < 64) {
        tx[tid] = txg[tid * HCONST + h];
        ty[tid] = tyg[tid * HCONST + h];
    }
    for (int j = tid; j < 512; j += 256)
        mk[j] = amask[b * SCONST + j] ? -INFINITY : 0.0f;

    int wid = tid >> 6, lane = tid & 63, quad = lane >> 4, l16 = lane & 15;

    const __bf16* qrow = qbuf + ((size_t)bh * SCONST + i0 + wid * 16 + l16) * DH;
    bf16x8 qf0 = *(const bf16x8*)(qrow + quad * 8);
    bf16x8 qf1 = *(const bf16x8*)(qrow + 32 + quad * 8);

    const __bf16* kg = kbuf + (size_t)bh * SCONST * DH;
    const __bf16* vg = vbuf + (size_t)bh * DH * SCONST;

    f32x4 O[4] = {};
    float m_r[4] = {-1e30f, -1e30f, -1e30f, -1e30f};
    float l_r[4] = {0.f, 0.f, 0.f, 0.f};

    __syncthreads();  // tp/tx/ty/mk ready

    for (int j0 = 0; j0 < SCONST; j0 += 64) {
        {
            const __bf16* kbase = kg + (size_t)j0 * DH;
#pragma unroll
            for (int s = 0; s < 2; s++) {
                int c = wid * 2 + s;
                gload16(kbase + c * 512 + lane * 8, Ks + c * 512);
                int dh = c * 8 + (lane >> 3), cc = lane & 7;
                gload16(vg + (size_t)dh * SCONST + j0 + cc * 8, Vs + c * 512);
            }
        }
        __syncthreads();

        float sc[4][4];  // [jt][r]
#pragma unroll
        for (int jt = 0; jt < 4; jt++) {
            f32x4 a = {};
            bf16x8 kf0 = *(const bf16x8*)&Ks[(jt * 16 + l16) * 64 + quad * 8];
            bf16x8 kf1 = *(const bf16x8*)&Ks[(jt * 16 + l16) * 64 + 32 + quad * 8];
            a = __builtin_amdgcn_mfma_f32_16x16x32_bf16(qf0, kf0, a, 0, 0, 0);
            a = __builtin_amdgcn_mfma_f32_16x16x32_bf16(qf1, kf1, a, 0, 0, 0);
#pragma unroll
            for (int r = 0; r < 4; r++) {
                int i = i0 + wid * 16 + quad * 4 + r;
                int j = j0 + jt * 16 + l16;
                int pk = idx[((size_t)b * SCONST + i) * SCONST + j];
                float bias = tp[pk & 31] + tx[(pk >> 5) & 63] + ty[(pk >> 11) & 63];
                sc[jt][r] = a[r] + bias + mk[j];
            }
        }

        float p[4][4];
#pragma unroll
        for (int r = 0; r < 4; r++) {
            float mb = fmaxf(fmaxf(sc[0][r], sc[1][r]), fmaxf(sc[2][r], sc[3][r]));
#pragma unroll
            for (int m = 1; m < 16; m <<= 1) mb = fmaxf(mb, __shfl_xor(mb, m, 64));
            float mn = fmaxf(m_r[r], mb);
            float alpha = __expf(m_r[r] - mn);
            m_r[r] = mn;
            float ls = 0.f;
#pragma unroll
            for (int jt = 0; jt < 4; jt++) {
                float pv = __expf(sc[jt][r] - mn);
                p[jt][r] = pv;
                ls += pv;
            }
#pragma unroll
            for (int m = 1; m < 16; m <<= 1) ls += __shfl_xor(ls, m, 64);
            l_r[r] = l_r[r] * alpha + ls;
#pragma unroll
            for (int nt = 0; nt < 4; nt++) O[nt][r] *= alpha;
        }

        __bf16* pl = &Ps[wid][0];
#pragma unroll
        for (int jt = 0; jt < 4; jt++)
#pragma unroll
            for (int r = 0; r < 4; r++)
                pl[(quad * 4 + r) * 64 + jt * 16 + l16] = (__bf16)p[jt][r];

        bf16x8 pa0 = *(const bf16x8*)&pl[l16 * 64 + quad * 8];
        bf16x8 pa1 = *(const bf16x8*)&pl[l16 * 64 + 32 + quad * 8];
#pragma unroll
        for (int nt = 0; nt < 4; nt++) {
            bf16x8 vb0 = *(const bf16x8*)&Vs[(nt * 16 + l16) * 64 + quad * 8];
            bf16x8 vb1 = *(const bf16x8*)&Vs[(nt * 16 + l16) * 64 + 32 + quad * 8];
            O[nt] = __builtin_amdgcn_mfma_f32_16x16x32_bf16(pa0, vb0, O[nt], 0, 0, 0);
            O[nt] = __builtin_amdgcn_mfma_f32_16x16x32_bf16(pa1, vb1, O[nt], 0, 0, 0);
        }
        __syncthreads();
    }

#pragma unroll
    for (int nt = 0; nt < 4; nt++)
#pragma unroll
        for (int r = 0; r < 4; r++) {
            int i = i0 + wid * 16 + quad * 4 + r;
            int dh = nt * 16 + l16;
            float o = O[nt][r] / l_r[r];
            ctx[((size_t)b * SCONST + i) * DCONST + h * DH + dh] = (__bf16)o;
        }
}

// ---------------------------------------------------------------------------
// fused split-K reduce (4 chunks) + bias + residual + LayerNorm over D=768
// ---------------------------------------------------------------------------
__global__ __launch_bounds__(256) void ln4_kernel(
        const float* __restrict__ part, const float* __restrict__ resid,
        const float* __restrict__ cbias, const float* __restrict__ g,
        const float* __restrict__ bb, float* __restrict__ outF,
        __bf16* __restrict__ outB) {
    const size_t MN = (size_t)4096 * DCONST;
    __shared__ float red[4];
    int row = blockIdx.x, t = threadIdx.x;
    size_t o = (size_t)row * DCONST;
    float v0, v1, v2;
    {
        int c0 = t, c1 = t + 256, c2 = t + 512;
        v0 = part[o + c0] + part[MN + o + c0] + part[2 * MN + o + c0] +
             part[3 * MN + o + c0] + cbias[c0] + resid[o + c0];
        v1 = part[o + c1] + part[MN + o + c1] + part[2 * MN + o + c1] +
             part[3 * MN + o + c1] + cbias[c1] + resid[o + c1];
        v2 = part[o + c2] + part[MN + o + c2] + part[2 * MN + o + c2] +
             part[3 * MN + o + c2] + cbias[c2] + resid[o + c2];
    }
    float s = v0 + v1 + v2;
#pragma unroll
    for (int m = 1; m < 64; m <<= 1) s += __shfl_xor(s, m, 64);
    if ((t & 63) == 0) red[t >> 6] = s;
    __syncthreads();
    s = red[0] + red[1] + red[2] + red[3];
    __syncthreads();
    float mu = s * (1.0f / 768.0f);
    float d0 = v0 - mu, d1 = v1 - mu, d2 = v2 - mu;
    float q = d0 * d0 + d1 * d1 + d2 * d2;
#pragma unroll
    for (int m = 1; m < 64; m <<= 1) q += __shfl_xor(q, m, 64);
    if ((t & 63) == 0) red[t >> 6] = q;
    __syncthreads();
    q = red[0] + red[1] + red[2] + red[3];
    float rstd = rsqrtf(q * (1.0f / 768.0f) + 1e-12f);
    float y0 = d0 * rstd * g[t] + bb[t];
    float y1 = d1 * rstd * g[t + 256] + bb[t + 256];
    float y2 = d2 * rstd * g[t + 512] + bb[t + 512];
    outF[o + t] = y0;
    outF[o + t + 256] = y1;
    outF[o + t + 512] = y2;
    outB[o + t] = (__bf16)y0;
    outB[o + t + 256] = (__bf16)y1;
    outB[o + t + 512] = (__bf16)y2;
}

// ---------------------------------------------------------------------------
extern "C" void kernel_launch(void* const* d_in, const int* in_sizes, int n_in,
                              void* d_out, int out_size, void* d_ws, size_t ws_size,
                              hipStream_t stream) {
    const float* hidden = (const float*)d_in[0];
    const int* amask = (const int*)d_in[1];
    const int* pos = (const int*)d_in[2];
    const int* bbox = (const int*)d_in[3];
    const float* qkv_w = (const float*)d_in[4];
    const float* q_bias = (const float*)d_in[5];
    const float* v_bias = (const float*)d_in[6];
    const float* aow = (const float*)d_in[7];
    const float* aob = (const float*)d_in[8];
    const float* ln1g = (const float*)d_in[9];
    const float* ln1b = (const float*)d_in[10];
    const float* iw = (const float*)d_in[11];
    const float* ib = (const float*)d_in[12];
    const float* fow = (const float*)d_in[13];
    const float* fob = (const float*)d_in[14];
    const float* ln2g = (const float*)d_in[15];
    const float* ln2b = (const float*)d_in[16];
    const float* tpt = (const float*)d_in[17];
    const float* txt = (const float*)d_in[18];
    const float* tyt = (const float*)d_in[19];
    float* out = (float*)d_out;

    char* w = (char*)d_ws;
    size_t used = 0;
    auto carve = [&](size_t bytes) {
        char* p = w + used;
        used += (bytes + 255) & ~(size_t)255;
        return p;
    };
    const size_t MT = 4096;  // B*S
    __bf16* qbuf = (__bf16*)carve(MT * 768 * 2);
    __bf16* kbuf = (__bf16*)carve(MT * 768 * 2);
    __bf16* vbuf = (__bf16*)carve(MT * 768 * 2);
    __bf16* xbf = (__bf16*)carve(MT * 768 * 2);
    __bf16* ctxbf = (__bf16*)carve(MT * 768 * 2);
    float* attnf = (float*)carve(MT * 768 * 4);
    __bf16* attnbf = (__bf16*)carve(MT * 768 * 2);
    __bf16* ffbf = (__bf16*)carve(MT * 3072 * 2);
    float* part = (float*)carve(4 * MT * 768 * 4);  // split-K partials (shared)
    int* idxb = (int*)carve((size_t)BCONST * SCONST * SCONST * 4);

    const size_t wq_sz = (size_t)2304 * 768 * 2;
    const size_t wa_sz = (size_t)768 * 768 * 2;
    const size_t wi_sz = (size_t)3072 * 768 * 2;
    const size_t wf_sz = (size_t)768 * 3072 * 2;
    const size_t wsum = wq_sz + wa_sz + wi_sz + wf_sz;
    bool full = (ws_size >= used + 12 * wsum + (12 * 4 + 4) * 256);
    int nlw = full ? 12 : 1;
    __bf16* wqT = (__bf16*)carve(wq_sz * nlw);
    __bf16* waT = (__bf16*)carve(wa_sz * nlw);
    __bf16* wiT = (__bf16*)carve(wi_sz * nlw);
    __bf16* wfT = (__bf16*)carve(wf_sz * nlw);

    build_idx_kernel<<<(BCONST * SCONST * SCONST) / 256, 256, 0, stream>>>(pos, bbox, idxb);
    cvt_kernel<<<(int)(MT * 768 / 256), 256, 0, stream>>>(hidden, xbf, (int)(MT * 768));

    if (full) {
        transpose_cvt_kernel<<<dim3((2304 / 32) * (768 / 32), 12), 256, 0, stream>>>(
                qkv_w, wqT, 768, 2304);
        transpose_cvt_kernel<<<dim3((768 / 32) * (768 / 32), 12), 256, 0, stream>>>(
                aow, waT, 768, 768);
        transpose_cvt_kernel<<<dim3((3072 / 32) * (768 / 32), 12), 256, 0, stream>>>(
                iw, wiT, 768, 3072);
        transpose_cvt_kernel<<<dim3((768 / 32) * (3072 / 32), 12), 256, 0, stream>>>(
                fow, wfT, 3072, 768);
    }

    for (int l = 0; l < LCONST; l++) {
        __bf16* wq_l = wqT + (full ? (size_t)l * 2304 * 768 : 0);
        __bf16* wa_l = waT + (full ? (size_t)l * 768 * 768 : 0);
        __bf16* wi_l = wiT + (full ? (size_t)l * 3072 * 768 : 0);
        __bf16* wf_l = wfT + (full ? (size_t)l * 768 * 3072 : 0);
        if (!full) {
            transpose_cvt_kernel<<<dim3((2304 / 32) * (768 / 32), 1), 256, 0, stream>>>(
                    qkv_w + (size_t)l * 768 * 2304, wq_l, 768, 2304);
            transpose_cvt_kernel<<<dim3((768 / 32) * (768 / 32), 1), 256, 0, stream>>>(
                    aow + (size_t)l * 768 * 768, wa_l, 768, 768);
            transpose_cvt_kernel<<<dim3((3072 / 32) * (768 / 32), 1), 256, 0, stream>>>(
                    iw + (size_t)l * 768 * 3072, wi_l, 768, 3072);
            transpose_cvt_kernel<<<dim3((768 / 32) * (3072 / 32), 1), 256, 0, stream>>>(
                    fow + (size_t)l * 3072 * 768, wf_l, 3072, 768);
        }

        // qkv: M=4096 N=2304 K=768
        gemm_kernel<0><<<dim3((4096 / 128) * (2304 / 128), 1), 256, 0, stream>>>(
                xbf, wq_l, 4096, 2304, 768, 768, q_bias + (size_t)l * 768,
                v_bias + (size_t)l * 768, nullptr, qbuf, kbuf, vbuf, nullptr);

        attn_kernel<<<BCONST * HCONST * (SCONST / 64), 256, 0, stream>>>(
                qbuf, kbuf, vbuf, idxb, amask, tpt, txt, tyt, ctxbf);

        // attn_out: M=4096 N=768 K=768, split-K x4 (Kc=192)
        gemm_kernel<4><<<dim3((4096 / 128) * (768 / 128), 4), 256, 0, stream>>>(
                ctxbf, wa_l, 4096, 768, 192, 768, nullptr, nullptr, part,
                nullptr, nullptr, nullptr, nullptr);
        const float* xres = (l == 0) ? hidden : out;
        ln4_kernel<<<4096, 256, 0, stream>>>(part, xres, aob + (size_t)l * 768,
                                             ln1g + (size_t)l * 768,
                                             ln1b + (size_t)l * 768, attnf, attnbf);

        // inter: M=4096 N=3072 K=768
        gemm_kernel<2><<<dim3((4096 / 128) * (3072 / 128), 1), 256, 0, stream>>>(
                attnbf, wi_l, 4096, 3072, 768, 768, ib + (size_t)l * 3072, nullptr,
                nullptr, nullptr, nullptr, nullptr, ffbf);

        // ffn_out: M=4096 N=768 K=3072, split-K x4 (Kc=768)
        gemm_kernel<4><<<dim3((4096 / 128) * (768 / 128), 4), 256, 0, stream>>>(
                ffbf, wf_l, 4096, 768, 768, 3072, nullptr, nullptr, part,
                nullptr, nullptr, nullptr, nullptr);
        ln4_kernel<<<4096, 256, 0, stream>>>(part, attnf, fob + (size_t)l * 768,
                                             ln2g + (size_t)l * 768,
                                             ln2b + (size_t)l * 768, out, xbf);
    }
}